// Round 4
// baseline (155.184 us; speedup 1.0000x reference)
//
#include <hip/hip_runtime.h>
#include <hip/hip_bf16.h>

using u16 = unsigned short;
typedef __bf16 bf16x8 __attribute__((ext_vector_type(8)));
typedef float f32x4 __attribute__((ext_vector_type(4)));

#define N_B   16
#define L_S   512
#define D_F   256
#define T_MEL 4096
#define M_TOT (N_B * L_S)
#define OUT_ELEMS ((size_t)N_B * T_MEL * D_F)   // fp32 elems
#define H1_ELEMS  ((size_t)M_TOT * D_F)         // bf16 elems
#define WP_ELEMS  (24 * 8192)                   // packed weight elems per conv
#define TBLK 128

__device__ __forceinline__ u16 f2bf(float f) {
  __hip_bfloat16 h = __float2bfloat16(f);
  return *(u16*)&h;
}

__device__ __forceinline__ bf16x8 bf8_zero() {
  uint4 z = make_uint4(0u, 0u, 0u, 0u);
  bf16x8 r;
  __builtin_memcpy(&r, &z, 16);
  return r;
}

__device__ __forceinline__ bf16x8 pack8(float4 v0, float4 v1) {
  union { bf16x8 h; u16 u[8]; } r;
  r.u[0] = f2bf(v0.x); r.u[1] = f2bf(v0.y); r.u[2] = f2bf(v0.z); r.u[3] = f2bf(v0.w);
  r.u[4] = f2bf(v1.x); r.u[5] = f2bf(v1.y); r.u[6] = f2bf(v1.z); r.u[7] = f2bf(v1.w);
  return r.h;
}

// ---------------------------------------------------------------------------
// Weight pack: wp[s][f][ki] = w[f][(s&7)*32+ki][s>>3]  (proven indexing).
// ---------------------------------------------------------------------------
__global__ __launch_bounds__(256)
void pack_kernel(const float* __restrict__ w1, const float* __restrict__ w2,
                 u16* __restrict__ wp1, u16* __restrict__ wp2) {
  int o   = (int)blockIdx.x * 256 + (int)threadIdx.x;   // 0..196607
  int s   = o >> 13;
  int rem = o & 8191;
  int f   = rem >> 5;
  int ki  = rem & 31;
  int d   = ((s & 7) << 5) + ki;
  int tap = s >> 3;
  int src = f * 768 + d * 3 + tap;
  wp1[o] = f2bf(w1[src]);
  wp2[o] = f2bf(w2[src]);
}

// ---------------------------------------------------------------------------
// Fused conv1d(K=3) im2col GEMM + bias + LN + ReLU.
// Round-4 structure: 512 blocks x 512 thr (8 waves). Waves 0-3 own the four
// 64-col slices for K-steps 0..11; waves 4-7 own the SAME slices for steps
// 12..23 (serial K-chain halved: 24 -> 12). Partials merged via padded LDS
// (one barrier, 2-way bank aliasing = free), then the proven 4-wave epilogue
// runs on waves 0-3 (barrier counts kept uniform across all 512 threads).
// Fragments stream straight from global (L2-resident) through a depth-3
// rotating register pipeline (~10 loads in flight/wave, no WAR on prefetch,
// all buffer indices compile-time). 4 waves/SIMD occupancy.
// ---------------------------------------------------------------------------
template<int STAGE>
__global__ __launch_bounds__(512)
void conv_ln_kernel(const float* __restrict__ Xf,  // stage-1 input (fp32)
                    const u16*  __restrict__ Xh,   // stage-2 input (bf16)
                    const u16*  __restrict__ Wp,
                    const float* __restrict__ cb,  const float* __restrict__ lgm,
                    const float* __restrict__ lbt, const float* __restrict__ lw,
                    const float* __restrict__ lb,  u16* __restrict__ Hout,
                    float* __restrict__ dpo)
{
  __shared__ float sBias[256], sG[256], sB[256], sLw[256];
  __shared__ float redS[4][16], redQ[4][16];
  __shared__ float up[4][16][68];        // padded: q-stride 272 dw = bank+16

  const int t = threadIdx.x;
  if (t < 256) {
    sBias[t] = cb[t];
    sG[t]    = lgm[t];
    sB[t]    = lbt[t];
    if (STAGE == 2) sLw[t] = lw[t];
  }
  __syncthreads();

  const int m0   = (int)blockIdx.x * 16; // 16-row tile
  const int n    = m0 >> 9;
  const int l0   = m0 & 511;
  const int wave = t >> 6, lane = t & 63;
  const int w4   = wave & 3;             // col-slice id 0..3
  const int half = wave >> 2;            // K-half: 0 => steps 0..11, 1 => 12..23
  const int wc   = w4 * 64;
  const int p    = lane & 15, q = lane >> 4;

  f32x4 acc[4];
  #pragma unroll
  for (int i = 0; i < 4; i++) acc[i] = (f32x4){0.f, 0.f, 0.f, 0.f};

  // ---- direct-from-global fragment loaders (proven indexing) ----
  auto LDA = [&](int s, bf16x8 &dst) {
    const int tap = s >> 3, dbase = (s & 7) << 5;
    const int lsrc = l0 + p + tap - 1;
    const bool ok = (unsigned)lsrc < 512u;
    const int lc = ok ? lsrc : 0;
    if (STAGE == 1) {
      const float* src = Xf + (((size_t)((n << 9) + lc)) << 8) + dbase + (q << 3);
      float4 v0 = *(const float4*)(src);
      float4 v1 = *(const float4*)(src + 4);
      dst = pack8(v0, v1);
    } else {
      dst = *(const bf16x8*)(Xh + (((size_t)((n << 9) + lc)) << 8) + dbase + (q << 3));
    }
    if (!ok) dst = bf8_zero();
  };
  auto LDB = [&](int s, bf16x8 (&b)[4]) {
    const u16* src = Wp + ((size_t)s << 13) + (size_t)p * 32 + (q << 3);
    #pragma unroll
    for (int ct = 0; ct < 4; ct++)
      b[ct] = *(const bf16x8*)(src + ((wc + ct * 16) << 5));
  };

  const int sbase = half * 12;
  bf16x8 aBuf[3];
  bf16x8 bBuf[3][4];
  LDA(sbase + 0, aBuf[0]); LDB(sbase + 0, bBuf[0]);
  LDA(sbase + 1, aBuf[1]); LDB(sbase + 1, bBuf[1]);

  #pragma unroll
  for (int i = 0; i < 12; i++) {
    const int cur = i % 3;
    const int nxt = (i + 2) % 3;
    if (i + 2 < 12) { LDA(sbase + i + 2, aBuf[nxt]); LDB(sbase + i + 2, bBuf[nxt]); }
    #pragma unroll
    for (int ct = 0; ct < 4; ct++)
      acc[ct] = __builtin_amdgcn_mfma_f32_16x16x32_bf16(aBuf[cur], bBuf[cur][ct], acc[ct], 0, 0, 0);
  }

  // ---- merge K-halves: upper waves park partials in LDS, lower adds ----
  if (half == 1) {
    #pragma unroll
    for (int ct = 0; ct < 4; ct++)
      #pragma unroll
      for (int j = 0; j < 4; j++)
        up[w4][q * 4 + j][ct * 16 + p] = acc[ct][j];
  }
  __syncthreads();
  if (half == 0) {
    #pragma unroll
    for (int ct = 0; ct < 4; ct++)
      #pragma unroll
      for (int j = 0; j < 4; j++)
        acc[ct][j] += up[w4][q * 4 + j][ct * 16 + p];
  }

  // ---- proven epilogue (waves 0-3 compute; barriers uniform) ----
  float s0[4] = {0,0,0,0}, s1[4] = {0,0,0,0};
  float mean[4], rstd[4];
  if (half == 0) {
    #pragma unroll
    for (int ct = 0; ct < 4; ct++) {
      float bias = sBias[wc + ct * 16 + p];
      #pragma unroll
      for (int j = 0; j < 4; j++) {
        float v = acc[ct][j] + bias;
        acc[ct][j] = v;
        s0[j] += v;
        s1[j] += v * v;
      }
    }
    #pragma unroll
    for (int m = 1; m <= 8; m <<= 1) {   // reduce across the 16 p-lanes
      #pragma unroll
      for (int j = 0; j < 4; j++) {
        s0[j] += __shfl_xor(s0[j], m);
        s1[j] += __shfl_xor(s1[j], m);
      }
    }
    if (p == 0) {
      #pragma unroll
      for (int j = 0; j < 4; j++) {
        redS[w4][q * 4 + j] = s0[j];
        redQ[w4][q * 4 + j] = s1[j];
      }
    }
  }
  __syncthreads();
  if (half == 0) {
    #pragma unroll
    for (int j = 0; j < 4; j++) {
      int r = q * 4 + j;
      float S = redS[0][r] + redS[1][r] + redS[2][r] + redS[3][r];
      float Q = redQ[0][r] + redQ[1][r] + redQ[2][r] + redQ[3][r];
      float mu  = S * (1.0f / 256.0f);
      float var = Q * (1.0f / 256.0f) - mu * mu;
      mean[j] = mu;
      rstd[j] = rsqrtf(var + 1e-5f);
    }
  }

  if (STAGE == 1) {
    if (half == 0) {
      #pragma unroll
      for (int ct = 0; ct < 4; ct++) {
        int c = wc + ct * 16 + p;
        float gg = sG[c], bb = sB[c];
        #pragma unroll
        for (int j = 0; j < 4; j++) {
          float v = (acc[ct][j] - mean[j]) * rstd[j] * gg + bb;
          v = fmaxf(v, 0.0f);
          Hout[(size_t)(m0 + q * 4 + j) * 256 + c] = f2bf(v);
        }
      }
    }
  } else {
    float ls[4] = {0,0,0,0};
    if (half == 0) {
      #pragma unroll
      for (int ct = 0; ct < 4; ct++) {
        int c = wc + ct * 16 + p;
        float gg = sG[c], bb = sB[c], ww = sLw[c];
        #pragma unroll
        for (int j = 0; j < 4; j++) {
          float v = (acc[ct][j] - mean[j]) * rstd[j] * gg + bb;
          v = fmaxf(v, 0.0f);
          ls[j] += v * ww;
        }
      }
      #pragma unroll
      for (int m = 1; m <= 8; m <<= 1) {
        #pragma unroll
        for (int j = 0; j < 4; j++) ls[j] += __shfl_xor(ls[j], m);
      }
    }
    __syncthreads();                     // redS free for reuse
    if (half == 0 && p == 0) {
      #pragma unroll
      for (int j = 0; j < 4; j++) redS[w4][q * 4 + j] = ls[j];
    }
    __syncthreads();
    if (t < 16) {
      float dv = fmaxf(redS[0][t] + redS[1][t] + redS[2][t] + redS[3][t] + lb[0], 0.0f);
      dpo[m0 + t] = dv;
    }
  }
}

// ---------------------------------------------------------------------------
// Length-regulate (fp32): parallel Hillis-Steele scan + binary search.
// Proven verbatim (output 0 bit-exact). Runs LAST (overwrites scratch in out).
// ---------------------------------------------------------------------------
__global__ __launch_bounds__(256)
void lr_kernel(const float* __restrict__ X, const int* __restrict__ tgt,
               float* __restrict__ out) {
  __shared__ int c[L_S];
  __shared__ int sidx[TBLK];
  const int t  = threadIdx.x;               // 0..255
  const int n  = blockIdx.x >> 5;           // 32 chunks per n
  const int t0 = (blockIdx.x & 31) * TBLK;

  c[t]       = tgt[n * L_S + t];
  c[t + 256] = tgt[n * L_S + t + 256];
  __syncthreads();
  for (int off = 1; off < L_S; off <<= 1) {
    int v0 = (t >= off) ? c[t - off] : 0;
    int i1 = t + 256;
    int v1 = (i1 >= off) ? c[i1 - off] : 0;
    __syncthreads();
    c[t]  += v0;
    c[i1] += v1;
    __syncthreads();
  }
  const int total = c[L_S - 1];
  if (t < TBLK) {
    int tt = t0 + t;
    int lo = 0, hi = L_S;
    while (lo < hi) {                       // upper_bound: first c[i] > tt
      int mid = (lo + hi) >> 1;
      if (c[mid] <= tt) lo = mid + 1; else hi = mid;
    }
    sidx[t] = (tt < total) ? lo : -1;
  }
  __syncthreads();

  #pragma unroll
  for (int i = 0; i < 32; i++) {
    int u   = t + i * 256;                  // 128 rows x 64 float4
    int dg  = u & 63;
    int tr  = u >> 6;
    int idx = sidx[tr];
    float4 v = make_float4(0.f, 0.f, 0.f, 0.f);
    if (idx >= 0)
      v = *(const float4*)(X + (((size_t)(n * L_S + idx)) << 8) + dg * 4);
    *(float4*)(out + (((size_t)(n * T_MEL + t0 + tr)) << 8) + dg * 4) = v;
  }
}

// ---------------------------------------------------------------------------
extern "C" void kernel_launch(void* const* d_in, const int* in_sizes, int n_in,
                              void* d_out, int out_size, void* d_ws, size_t ws_size,
                              hipStream_t stream) {
  (void)d_ws; (void)ws_size; (void)in_sizes; (void)n_in; (void)out_size;

  const float* x   = (const float*)d_in[0];
  const float* w1  = (const float*)d_in[1];
  const float* b1  = (const float*)d_in[2];
  const float* g1  = (const float*)d_in[3];
  const float* be1 = (const float*)d_in[4];
  const float* w2  = (const float*)d_in[5];
  const float* b2  = (const float*)d_in[6];
  const float* g2  = (const float*)d_in[7];
  const float* be2 = (const float*)d_in[8];
  const float* lw  = (const float*)d_in[9];
  const float* lb  = (const float*)d_in[10];
  const int*   tgt = (const int*)d_in[11];

  float* out = (float*)d_out;
  float* dpo = out + OUT_ELEMS;

  // bf16 scratch inside the fp32 output-0 region; overwritten by final LR.
  u16* h1  = (u16*)d_out;
  u16* wp1 = h1 + H1_ELEMS;
  u16* wp2 = wp1 + WP_ELEMS;

  pack_kernel<<<768, 256, 0, stream>>>(w1, w2, wp1, wp2);
  conv_ln_kernel<1><<<M_TOT / 16, 512, 0, stream>>>(
      x, nullptr, wp1, b1, g1, be1, nullptr, nullptr, h1, nullptr);
  conv_ln_kernel<2><<<M_TOT / 16, 512, 0, stream>>>(
      nullptr, h1, wp2, b2, g2, be2, lw, lb, nullptr, dpo);
  lr_kernel<<<N_B * (T_MEL / TBLK), 256, 0, stream>>>(x, tgt, out);
}

// Round 5
// 142.326 us; speedup vs baseline: 1.0903x; 1.0903x over previous
//
#include <hip/hip_runtime.h>
#include <hip/hip_bf16.h>

using u16 = unsigned short;
typedef __bf16 bf16x8 __attribute__((ext_vector_type(8)));
typedef float f32x4 __attribute__((ext_vector_type(4)));

#define N_B   16
#define L_S   512
#define D_F   256
#define T_MEL 4096
#define M_TOT (N_B * L_S)
#define OUT_ELEMS ((size_t)N_B * T_MEL * D_F)   // fp32 elems
#define H1_ELEMS  ((size_t)M_TOT * D_F)         // bf16 elems
#define WP_ELEMS  (24 * 8192)                   // packed weight elems per conv
#define TBLK 128

__device__ __forceinline__ u16 f2bf(float f) {
  __hip_bfloat16 h = __float2bfloat16(f);
  return *(u16*)&h;
}

__device__ __forceinline__ bf16x8 pack8(float4 v0, float4 v1) {
  union { bf16x8 h; u16 u[8]; } r;
  r.u[0] = f2bf(v0.x); r.u[1] = f2bf(v0.y); r.u[2] = f2bf(v0.z); r.u[3] = f2bf(v0.w);
  r.u[4] = f2bf(v1.x); r.u[5] = f2bf(v1.y); r.u[6] = f2bf(v1.z); r.u[7] = f2bf(v1.w);
  return r.h;
}

// ---------------------------------------------------------------------------
// Weight pack: wp[s][f][ki] = w[f][(s&7)*32+ki][s>>3]  (proven indexing).
// ---------------------------------------------------------------------------
__global__ __launch_bounds__(256)
void pack_kernel(const float* __restrict__ w1, const float* __restrict__ w2,
                 u16* __restrict__ wp1, u16* __restrict__ wp2) {
  int o   = (int)blockIdx.x * 256 + (int)threadIdx.x;   // 0..196607
  int s   = o >> 13;
  int rem = o & 8191;
  int f   = rem >> 5;
  int ki  = rem & 31;
  int d   = ((s & 7) << 5) + ki;
  int tap = s >> 3;
  int src = f * 768 + d * 3 + tap;
  wp1[o] = f2bf(w1[src]);
  wp2[o] = f2bf(w2[src]);
}

// ---------------------------------------------------------------------------
// Fused conv1d(K=3) im2col GEMM + bias + LN + ReLU — LINE-REQUEST-MINIMIZED.
// R3==R4 null showed the loop is bound by per-CU cacheline request rate
// (~5.3 cy/line at ~15.4K lines/CU), not latency or occupancy. This version
// cuts requests via reuse: 256 blocks (1/CU) x 32 rows x 256 cols;
// A staged ONCE in LDS (34 rows, pad stride 264 -> m97-class 8-way banks);
// B (16KB/step) double-buffered through LDS, loads issued a full step early
// (T14 split: issue -> frags+MFMA -> barrier -> ds_write -> barrier).
// Per-CU lines: ~15.4K -> ~6.7K. 8 waves = 2 row-halves x 4 col-slices;
// each wave keeps the PROVEN 16x64 fragment shape + epilogue math.
// ---------------------------------------------------------------------------
template<int STAGE>
__global__ __launch_bounds__(512)
void conv_ln_kernel(const float* __restrict__ Xf,  // stage-1 input (fp32)
                    const u16*  __restrict__ Xh,   // stage-2 input (bf16)
                    const u16*  __restrict__ Wp,
                    const float* __restrict__ cb,  const float* __restrict__ lgm,
                    const float* __restrict__ lbt, const float* __restrict__ lw,
                    const float* __restrict__ lb,  u16* __restrict__ Hout,
                    float* __restrict__ dpo)
{
  __shared__ __align__(16) u16 As[34 * 264 + 8];   // 18.0 KB, stride 264
  __shared__ __align__(16) u16 Bs[2 * 8192];       // 32 KB, 2 x 16KB step tiles
  __shared__ float sBias[256], sG[256], sB[256], sLw[256];
  __shared__ float redS[2][4][16], redQ[2][4][16];

  const int t = threadIdx.x;
  if (t < 256) {
    sBias[t] = cb[t];
    sG[t]    = lgm[t];
    sB[t]    = lbt[t];
    if (STAGE == 2) sLw[t] = lw[t];
  }

  const int m0   = (int)blockIdx.x * 32;  // 32-row tile
  const int n    = m0 >> 9;
  const int l0   = m0 & 511;
  const int wave = t >> 6, lane = t & 63;
  const int cs   = wave & 3;              // col-slice 0..3
  const int rh   = wave >> 2;             // row-half 0..1
  const int wc   = cs * 64;
  const int rh16 = rh * 16;
  const int p    = lane & 15, q = lane >> 4;

  // ---- stage A once: rows l0-1 .. l0+32 (34 rows x 256 elems, bf16) ----
  for (int c = t; c < 1088; c += 512) {   // 34 rows x 32 chunks of 8 elems
    int row  = c >> 5;
    int col8 = c & 31;
    int l    = l0 + row - 1;
    uint4 val;
    if ((unsigned)l < 512u) {
      if (STAGE == 1) {
        const float* src = Xf + (((size_t)((n << 9) + l)) << 8) + (col8 << 3);
        float4 v0 = *(const float4*)src;
        float4 v1 = *(const float4*)(src + 4);
        bf16x8 pk = pack8(v0, v1);
        __builtin_memcpy(&val, &pk, 16);
      } else {
        val = *(const uint4*)(Xh + (((size_t)((n << 9) + l)) << 8) + (col8 << 3));
      }
    } else {
      val = make_uint4(0u, 0u, 0u, 0u);
    }
    *(uint4*)(As + row * 264 + (col8 << 3)) = val;
  }
  // ---- stage B step 0 into buf 0 (16KB, 512 thr x 2 x 16B, linear) ----
  {
    uint4 r0 = *(const uint4*)(Wp + (t << 3));
    uint4 r1 = *(const uint4*)(Wp + ((t + 512) << 3));
    *(uint4*)(Bs + (t << 3))         = r0;
    *(uint4*)(Bs + ((t + 512) << 3)) = r1;
  }
  __syncthreads();

  f32x4 acc[4];
  #pragma unroll
  for (int i = 0; i < 4; i++) acc[i] = (f32x4){0.f, 0.f, 0.f, 0.f};

  for (int s = 0; s < 24; s++) {
    const int cur = s & 1;
    // (a) issue global loads for step s+1 (consumed at (d) -> ~full step of flight)
    uint4 r0, r1;
    if (s < 23) {
      const u16* src = Wp + ((size_t)(s + 1) << 13);
      r0 = *(const uint4*)(src + (t << 3));
      r1 = *(const uint4*)(src + ((t + 512) << 3));
    }
    // (b) fragments from LDS + MFMA
    {
      const u16* bs = Bs + (cur << 13);
      const int tap = s >> 3, dbase = (s & 7) << 5;
      bf16x8 af = *(const bf16x8*)(As + (rh16 + p + tap) * 264 + dbase + (q << 3));
      #pragma unroll
      for (int ct = 0; ct < 4; ct++) {
        bf16x8 bfr = *(const bf16x8*)(bs + ((wc + ct * 16 + p) << 5) + (q << 3));
        acc[ct] = __builtin_amdgcn_mfma_f32_16x16x32_bf16(af, bfr, acc[ct], 0, 0, 0);
      }
    }
    // (c,d,e) reads of buf[cur^1] finished last step; publish step s+1
    if (s < 23) {
      __syncthreads();
      *(uint4*)(Bs + ((cur ^ 1) << 13) + (t << 3))         = r0;
      *(uint4*)(Bs + ((cur ^ 1) << 13) + ((t + 512) << 3)) = r1;
      __syncthreads();
    }
  }

  // ---- bias + per-row sum / sumsq over this wave's 64 cols (proven math) ----
  float s0[4] = {0,0,0,0}, s1[4] = {0,0,0,0};
  #pragma unroll
  for (int ct = 0; ct < 4; ct++) {
    float bias = sBias[wc + ct * 16 + p];
    #pragma unroll
    for (int j = 0; j < 4; j++) {
      float v = acc[ct][j] + bias;
      acc[ct][j] = v;
      s0[j] += v;
      s1[j] += v * v;
    }
  }
  #pragma unroll
  for (int m = 1; m <= 8; m <<= 1) {      // reduce across the 16 p-lanes
    #pragma unroll
    for (int j = 0; j < 4; j++) {
      s0[j] += __shfl_xor(s0[j], m);
      s1[j] += __shfl_xor(s1[j], m);
    }
  }
  if (p == 0) {
    #pragma unroll
    for (int j = 0; j < 4; j++) {
      redS[rh][cs][q * 4 + j] = s0[j];
      redQ[rh][cs][q * 4 + j] = s1[j];
    }
  }
  __syncthreads();
  float mean[4], rstd[4];
  #pragma unroll
  for (int j = 0; j < 4; j++) {
    int r = q * 4 + j;
    float S = redS[rh][0][r] + redS[rh][1][r] + redS[rh][2][r] + redS[rh][3][r];
    float Q = redQ[rh][0][r] + redQ[rh][1][r] + redQ[rh][2][r] + redQ[rh][3][r];
    float mu  = S * (1.0f / 256.0f);
    float var = Q * (1.0f / 256.0f) - mu * mu;
    mean[j] = mu;
    rstd[j] = rsqrtf(var + 1e-5f);
  }

  if (STAGE == 1) {
    #pragma unroll
    for (int ct = 0; ct < 4; ct++) {
      int c = wc + ct * 16 + p;
      float gg = sG[c], bb = sB[c];
      #pragma unroll
      for (int j = 0; j < 4; j++) {
        float v = (acc[ct][j] - mean[j]) * rstd[j] * gg + bb;
        v = fmaxf(v, 0.0f);
        Hout[(size_t)(m0 + rh16 + q * 4 + j) * 256 + c] = f2bf(v);
      }
    }
  } else {
    float ls[4] = {0,0,0,0};
    #pragma unroll
    for (int ct = 0; ct < 4; ct++) {
      int c = wc + ct * 16 + p;
      float gg = sG[c], bb = sB[c], ww = sLw[c];
      #pragma unroll
      for (int j = 0; j < 4; j++) {
        float v = (acc[ct][j] - mean[j]) * rstd[j] * gg + bb;
        v = fmaxf(v, 0.0f);
        ls[j] += v * ww;
      }
    }
    #pragma unroll
    for (int m = 1; m <= 8; m <<= 1) {
      #pragma unroll
      for (int j = 0; j < 4; j++) ls[j] += __shfl_xor(ls[j], m);
    }
    __syncthreads();                      // done reading redS for mean/var
    if (p == 0) {
      #pragma unroll
      for (int j = 0; j < 4; j++) redS[rh][cs][q * 4 + j] = ls[j];
    }
    __syncthreads();
    if (t < 32) {
      int r2 = t >> 4, ri = t & 15;
      float dv = fmaxf(redS[r2][0][ri] + redS[r2][1][ri] +
                       redS[r2][2][ri] + redS[r2][3][ri] + lb[0], 0.0f);
      dpo[m0 + t] = dv;
    }
  }
}

// ---------------------------------------------------------------------------
// Length-regulate (fp32): parallel Hillis-Steele scan + binary search.
// Proven verbatim (output 0 bit-exact). Runs LAST (overwrites scratch in out).
// ---------------------------------------------------------------------------
__global__ __launch_bounds__(256)
void lr_kernel(const float* __restrict__ X, const int* __restrict__ tgt,
               float* __restrict__ out) {
  __shared__ int c[L_S];
  __shared__ int sidx[TBLK];
  const int t  = threadIdx.x;               // 0..255
  const int n  = blockIdx.x >> 5;           // 32 chunks per n
  const int t0 = (blockIdx.x & 31) * TBLK;

  c[t]       = tgt[n * L_S + t];
  c[t + 256] = tgt[n * L_S + t + 256];
  __syncthreads();
  for (int off = 1; off < L_S; off <<= 1) {
    int v0 = (t >= off) ? c[t - off] : 0;
    int i1 = t + 256;
    int v1 = (i1 >= off) ? c[i1 - off] : 0;
    __syncthreads();
    c[t]  += v0;
    c[i1] += v1;
    __syncthreads();
  }
  const int total = c[L_S - 1];
  if (t < TBLK) {
    int tt = t0 + t;
    int lo = 0, hi = L_S;
    while (lo < hi) {                       // upper_bound: first c[i] > tt
      int mid = (lo + hi) >> 1;
      if (c[mid] <= tt) lo = mid + 1; else hi = mid;
    }
    sidx[t] = (tt < total) ? lo : -1;
  }
  __syncthreads();

  #pragma unroll
  for (int i = 0; i < 32; i++) {
    int u   = t + i * 256;                  // 128 rows x 64 float4
    int dg  = u & 63;
    int tr  = u >> 6;
    int idx = sidx[tr];
    float4 v = make_float4(0.f, 0.f, 0.f, 0.f);
    if (idx >= 0)
      v = *(const float4*)(X + (((size_t)(n * L_S + idx)) << 8) + dg * 4);
    *(float4*)(out + (((size_t)(n * T_MEL + t0 + tr)) << 8) + dg * 4) = v;
  }
}

// ---------------------------------------------------------------------------
extern "C" void kernel_launch(void* const* d_in, const int* in_sizes, int n_in,
                              void* d_out, int out_size, void* d_ws, size_t ws_size,
                              hipStream_t stream) {
  (void)d_ws; (void)ws_size; (void)in_sizes; (void)n_in; (void)out_size;

  const float* x   = (const float*)d_in[0];
  const float* w1  = (const float*)d_in[1];
  const float* b1  = (const float*)d_in[2];
  const float* g1  = (const float*)d_in[3];
  const float* be1 = (const float*)d_in[4];
  const float* w2  = (const float*)d_in[5];
  const float* b2  = (const float*)d_in[6];
  const float* g2  = (const float*)d_in[7];
  const float* be2 = (const float*)d_in[8];
  const float* lw  = (const float*)d_in[9];
  const float* lb  = (const float*)d_in[10];
  const int*   tgt = (const int*)d_in[11];

  float* out = (float*)d_out;
  float* dpo = out + OUT_ELEMS;

  // bf16 scratch inside the fp32 output-0 region; overwritten by final LR.
  u16* h1  = (u16*)d_out;
  u16* wp1 = h1 + H1_ELEMS;
  u16* wp2 = wp1 + WP_ELEMS;

  pack_kernel<<<768, 256, 0, stream>>>(w1, w2, wp1, wp2);
  conv_ln_kernel<1><<<M_TOT / 32, 512, 0, stream>>>(
      x, nullptr, wp1, b1, g1, be1, nullptr, nullptr, h1, nullptr);
  conv_ln_kernel<2><<<M_TOT / 32, 512, 0, stream>>>(
      nullptr, h1, wp2, b2, g2, be2, lw, lb, nullptr, dpo);
  lr_kernel<<<N_B * (T_MEL / TBLK), 256, 0, stream>>>(x, tgt, out);
}